// Round 3
// baseline (208.872 us; speedup 1.0000x reference)
//
#include <hip/hip_runtime.h>
#include <hip/hip_bf16.h>

#define DDIM    128
#define NPAIRS  8128
#define NROWS   131072
#define NCHUNK  64
#define CPAIRS  127                 // pairs per chunk
#define MATELEM 16384               // elements per plane (128x128)
#define MSTRIDE (4 * MATELEM)       // planes per mat: RM_hi, RM_lo, CM_hi, CM_lo

typedef __attribute__((ext_vector_type(8))) short bf16x8;
typedef __attribute__((ext_vector_type(4))) float f32x4;
typedef __attribute__((ext_vector_type(4))) unsigned short u16x4;

__device__ inline unsigned short f32_to_bf16_rne(float f) {
    unsigned u = __float_as_uint(f);
    u += 0x7fffu + ((u >> 16) & 1u);   // round-to-nearest-even (finite inputs)
    return (unsigned short)(u >> 16);
}
__device__ inline float bf16_to_f32(unsigned short h) {
    return __uint_as_float((unsigned)h << 16);
}
// v ~= hi + lo with |residual| ~ 2^-18 * |v|
__device__ inline void bsplit(float v, unsigned short& hi, unsigned short& lo) {
    hi = f32_to_bf16_rne(v);
    lo = f32_to_bf16_rne(v - bf16_to_f32(hi));
}

// ---------------------------------------------------------------------------
// Kernel 1: block c builds M_c = prod of its 127 Givens rotations (fp32 in
// LDS, thread t owns row t, stride 129 -> chain reads bank (t+j)%32 distinct).
// Emits 4 bf16 planes: row-major hi/lo + col-major hi/lo.
// ---------------------------------------------------------------------------
__global__ __launch_bounds__(256) void chunk_kernel(
        const float* __restrict__ theta,
        const int*   __restrict__ pairs,
        unsigned short* __restrict__ buf) {
    __shared__ float  R[DDIM * (DDIM + 1)];
    __shared__ float2 cs[CPAIRS];
    __shared__ int2   ij[CPAIRS];

    const int t  = threadIdx.x;
    const int c  = blockIdx.x;
    const int p0 = c * CPAIRS;

    if (t < CPAIRS) {
        float th = theta[p0 + t];
        cs[t] = make_float2(cosf(th), sinf(th));
        ij[t] = make_int2(pairs[2 * (p0 + t)], pairs[2 * (p0 + t) + 1]);
    }
    if (t < DDIM) {
        float* row = &R[t * (DDIM + 1)];
        for (int q = 0; q < DDIM; ++q) row[q] = (q == t) ? 1.0f : 0.0f;
    }
    __syncthreads();

    if (t < DDIM) {
        float* row = &R[t * (DDIM + 1)];
        int   cur_i = ij[0].x;
        float ri    = row[cur_i];
        for (int p = 0; p < CPAIRS; ++p) {
            int2   v = ij[p];
            float2 a = cs[p];
            if (v.x != cur_i) {        // wave-uniform transition
                row[cur_i] = ri;
                cur_i = v.x;
                ri = row[cur_i];
            }
            float rj = row[v.y];
            row[v.y] = fmaf(a.y, ri, a.x * rj);      // s*xi + c*xj
            ri       = fmaf(a.x, ri, -(a.y * rj));   // c*xi - s*xj
        }
        row[cur_i] = ri;
    }
    __syncthreads();

    unsigned short* dst = buf + (size_t)c * MSTRIDE;
    // row-major planes (coalesced u16 stores; LDS stride-1 reads)
    for (int oi = t; oi < MATELEM; oi += 256) {
        int r = oi >> 7, q = oi & 127;
        unsigned short hi, lo;
        bsplit(R[r * (DDIM + 1) + q], hi, lo);
        dst[oi]           = hi;
        dst[MATELEM + oi] = lo;
    }
    // col-major planes (coalesced stores; LDS banks (r+q)%32 distinct)
    for (int oi = t; oi < MATELEM; oi += 256) {
        int q = oi >> 7, r = oi & 127;   // cm index = col*128 + row
        unsigned short hi, lo;
        bsplit(R[r * (DDIM + 1) + q], hi, lo);
        dst[2 * MATELEM + oi] = hi;
        dst[3 * MATELEM + oi] = lo;
    }
}

// ---------------------------------------------------------------------------
// Kernel 2: in-place binary tree level. Block b: slot i0 = (2b)<<level gets
// src[i0] . src[i1], i1 = i0 + (1<<level). Split-precision: 3 MFMAs per
// fragment pair. A-frags = vector loads from i0's row-major planes (own rows
// only -> in-place write after the k-loop is race-free); B-frags = vector
// loads from i1's col-major planes. 8 waves, 16 output rows per wave.
// ---------------------------------------------------------------------------
__global__ __launch_bounds__(512) void combine_kernel(
        unsigned short* __restrict__ buf, int level) {
    const int lane = threadIdx.x & 63;
    const int wave = threadIdx.x >> 6;
    const int lrow = lane & 15;
    const int lkhi = lane >> 4;
    const size_t i0 = (size_t)(2 * blockIdx.x) << level;
    const size_t i1 = i0 + ((size_t)1 << level);

    unsigned short* D = buf + i0 * MSTRIDE;            // A source & in-place dst
    const unsigned short* Bcm = buf + i1 * MSTRIDE + 2 * MATELEM;

    const int row0 = wave * 16;
    f32x4 acc[8];
    #pragma unroll
    for (int n = 0; n < 8; ++n) acc[n] = (f32x4){0.0f, 0.0f, 0.0f, 0.0f};

    #pragma unroll
    for (int kstep = 0; kstep < 4; ++kstep) {
        const int k0 = kstep * 32 + lkhi * 8;
        const unsigned short* ap = D + (size_t)(row0 + lrow) * DDIM + k0;
        bf16x8 ahi = *reinterpret_cast<const bf16x8*>(ap);
        bf16x8 alo = *reinterpret_cast<const bf16x8*>(ap + MATELEM);
        #pragma unroll
        for (int n = 0; n < 8; ++n) {
            const unsigned short* bp = Bcm + (size_t)(n * 16 + lrow) * DDIM + k0;
            bf16x8 bhi = *reinterpret_cast<const bf16x8*>(bp);
            bf16x8 blo = *reinterpret_cast<const bf16x8*>(bp + MATELEM);
            acc[n] = __builtin_amdgcn_mfma_f32_16x16x32_bf16(ahi, bhi, acc[n], 0, 0, 0);
            acc[n] = __builtin_amdgcn_mfma_f32_16x16x32_bf16(alo, bhi, acc[n], 0, 0, 0);
            acc[n] = __builtin_amdgcn_mfma_f32_16x16x32_bf16(ahi, blo, acc[n], 0, 0, 0);
        }
    }

    // C/D layout: row = row0 + lkhi*4 + r, col = n*16 + lrow
    #pragma unroll
    for (int n = 0; n < 8; ++n) {
        const int col = n * 16 + lrow;
        u16x4 chi, clo;
        #pragma unroll
        for (int r = 0; r < 4; ++r) {
            const int orow = row0 + lkhi * 4 + r;
            unsigned short hi, lo;
            bsplit(acc[n][r], hi, lo);
            D[orow * DDIM + col]           = hi;
            D[MATELEM + orow * DDIM + col] = lo;
            chi[r] = hi; clo[r] = lo;
        }
        const size_t cmoff = 2 * MATELEM + (size_t)col * DDIM + row0 + lkhi * 4;
        *reinterpret_cast<u16x4*>(D + cmoff)           = chi;
        *reinterpret_cast<u16x4*>(D + cmoff + MATELEM) = clo;
    }
}

// ---------------------------------------------------------------------------
// Kernel 3: out = x @ (Rhi + Rlo).  A-frags from nontemporal fp32 loads of x
// (bf16 in-register), B-frags = vector loads from slot-0 col-major planes
// (L2-resident).  Block = 4 waves x (32 rows x 128 cols) = 128 rows.
// ---------------------------------------------------------------------------
__global__ __launch_bounds__(256) void gemm_kernel(
        const float* __restrict__ x,
        const unsigned short* __restrict__ Bcm,   // cm_hi; cm_lo at +MATELEM
        float* __restrict__ out) {
    const int lane = threadIdx.x & 63;
    const int wave = threadIdx.x >> 6;
    const int lrow = lane & 15;
    const int lkhi = lane >> 4;
    const long brow = (long)blockIdx.x * 128 + wave * 32;

    f32x4 acc[2][8];
    #pragma unroll
    for (int m = 0; m < 2; ++m)
        #pragma unroll
        for (int n = 0; n < 8; ++n)
            acc[m][n] = (f32x4){0.0f, 0.0f, 0.0f, 0.0f};

    #pragma unroll
    for (int kstep = 0; kstep < 4; ++kstep) {
        const int k0 = kstep * 32 + lkhi * 8;
        bf16x8 afr[2];
        #pragma unroll
        for (int m = 0; m < 2; ++m) {
            const float* src = x + (brow + m * 16 + lrow) * (long)DDIM + k0;
            f32x4 lo = __builtin_nontemporal_load(reinterpret_cast<const f32x4*>(src));
            f32x4 hi = __builtin_nontemporal_load(reinterpret_cast<const f32x4*>(src + 4));
            union { bf16x8 v; unsigned short u[8]; } ua;
            #pragma unroll
            for (int e = 0; e < 4; ++e) {
                ua.u[e]     = f32_to_bf16_rne(lo[e]);
                ua.u[e + 4] = f32_to_bf16_rne(hi[e]);
            }
            afr[m] = ua.v;
        }
        #pragma unroll
        for (int n = 0; n < 8; ++n) {
            const unsigned short* bp = Bcm + (size_t)(n * 16 + lrow) * DDIM + k0;
            bf16x8 bhi = *reinterpret_cast<const bf16x8*>(bp);
            bf16x8 blo = *reinterpret_cast<const bf16x8*>(bp + MATELEM);
            acc[0][n] = __builtin_amdgcn_mfma_f32_16x16x32_bf16(afr[0], bhi, acc[0][n], 0, 0, 0);
            acc[0][n] = __builtin_amdgcn_mfma_f32_16x16x32_bf16(afr[0], blo, acc[0][n], 0, 0, 0);
            acc[1][n] = __builtin_amdgcn_mfma_f32_16x16x32_bf16(afr[1], bhi, acc[1][n], 0, 0, 0);
            acc[1][n] = __builtin_amdgcn_mfma_f32_16x16x32_bf16(afr[1], blo, acc[1][n], 0, 0, 0);
        }
    }

    // C/D layout: row = (lane>>4)*4 + r, col = lane&15 per 16x16 tile
    #pragma unroll
    for (int m = 0; m < 2; ++m) {
        #pragma unroll
        for (int r = 0; r < 4; ++r) {
            const long orow = brow + m * 16 + lkhi * 4 + r;
            #pragma unroll
            for (int n = 0; n < 8; ++n) {
                __builtin_nontemporal_store(acc[m][n][r],
                                            &out[orow * DDIM + n * 16 + lrow]);
            }
        }
    }
}

extern "C" void kernel_launch(void* const* d_in, const int* in_sizes, int n_in,
                              void* d_out, int out_size, void* d_ws, size_t ws_size,
                              hipStream_t stream) {
    (void)in_sizes; (void)n_in; (void)out_size; (void)ws_size;
    const float* x     = (const float*)d_in[0];
    const float* theta = (const float*)d_in[1];
    const int*   pairs = (const int*)d_in[2];
    float* out = (float*)d_out;

    // ws: 64 mats x 4 planes x 16384 bf16 = 8 MB. In-place tree: level l
    // block b consumes slots (2b)<<l and (2b+1)<<l, writes (2b)<<l.
    unsigned short* buf = (unsigned short*)d_ws;

    chunk_kernel<<<NCHUNK, 256, 0, stream>>>(theta, pairs, buf);
    for (int l = 0; l < 6; ++l)
        combine_kernel<<<(NCHUNK / 2) >> l, 512, 0, stream>>>(buf, l);
    // final R lives in slot 0; gemm reads its col-major hi/lo planes
    gemm_kernel<<<NROWS / 128, 256, 0, stream>>>(x, buf + 2 * MATELEM, out);
}

// Round 4
// 146.012 us; speedup vs baseline: 1.4305x; 1.4305x over previous
//
#include <hip/hip_runtime.h>
#include <hip/hip_bf16.h>

#define DDIM    128
#define NPAIRS  8128
#define NROWS   131072
#define NCHUNK  64
#define CPAIRS  127                 // pairs per chunk
#define MATELEM 16384               // elements per plane (128x128)
#define MSTRIDE (4 * MATELEM)       // planes per slot: A_hi, A_lo, B_hi, B_lo

typedef __attribute__((ext_vector_type(8))) short bf16x8;
typedef __attribute__((ext_vector_type(4))) float f32x4;
typedef __attribute__((ext_vector_type(4))) unsigned short u16x4;

// Fragment layouts for mfma_f32_16x16x32_bf16 (verified m89 mapping):
//  A-plane: value M[row][k]  at ((row>>4)*4 + (k>>5))*512 + (((k>>3)&3)*16 + (row&15))*8 + (k&7)
//  B-plane: value M[k][col]  at ((col>>4)*4 + (k>>5))*512 + (((k>>3)&3)*16 + (col&15))*8 + (k&7)
// -> per-lane loads are contiguous 16B; a wave's (tile,kstep) block is one 8KB region.

__device__ inline unsigned short f32_to_bf16_rne(float f) {
    unsigned u = __float_as_uint(f);
    u += 0x7fffu + ((u >> 16) & 1u);   // round-to-nearest-even (finite inputs)
    return (unsigned short)(u >> 16);
}
__device__ inline float bf16_to_f32(unsigned short h) {
    return __uint_as_float((unsigned)h << 16);
}
// v ~= hi + lo, |residual| ~ 2^-18 |v|
__device__ inline void bsplit(float v, unsigned short& hi, unsigned short& lo) {
    hi = f32_to_bf16_rne(v);
    lo = f32_to_bf16_rne(v - bf16_to_f32(hi));
}

// ---------------------------------------------------------------------------
// Kernel 1: block c builds M_c = prod of its 127 Givens rotations (fp32 in
// LDS, thread t owns row t, stride 129). Emits A-frag hi/lo + B-frag hi/lo.
// ---------------------------------------------------------------------------
__global__ __launch_bounds__(256) void chunk_kernel(
        const float* __restrict__ theta,
        const int*   __restrict__ pairs,
        unsigned short* __restrict__ buf) {
    __shared__ float  R[DDIM * (DDIM + 1)];
    __shared__ float2 cs[CPAIRS];
    __shared__ int2   ij[CPAIRS];

    const int t  = threadIdx.x;
    const int c  = blockIdx.x;
    const int p0 = c * CPAIRS;

    if (t < CPAIRS) {
        float th = theta[p0 + t];
        cs[t] = make_float2(cosf(th), sinf(th));
        ij[t] = make_int2(pairs[2 * (p0 + t)], pairs[2 * (p0 + t) + 1]);
    }
    if (t < DDIM) {
        float* row = &R[t * (DDIM + 1)];
        for (int q = 0; q < DDIM; ++q) row[q] = (q == t) ? 1.0f : 0.0f;
    }
    __syncthreads();

    if (t < DDIM) {
        float* row = &R[t * (DDIM + 1)];
        int   cur_i = ij[0].x;
        float ri    = row[cur_i];
        for (int p = 0; p < CPAIRS; ++p) {
            int2   v = ij[p];
            float2 a = cs[p];
            if (v.x != cur_i) {        // wave-uniform transition
                row[cur_i] = ri;
                cur_i = v.x;
                ri = row[cur_i];
            }
            float rj = row[v.y];
            row[v.y] = fmaf(a.y, ri, a.x * rj);      // s*xi + c*xj
            ri       = fmaf(a.x, ri, -(a.y * rj));   // c*xi - s*xj
        }
        row[cur_i] = ri;
    }
    __syncthreads();

    unsigned short* dst = buf + (size_t)c * MSTRIDE;
    // A-frag planes: slot oi -> row/k
    for (int oi = t; oi < MATELEM; oi += 256) {
        int e = oi & 7, lane = (oi >> 3) & 63, ks = (oi >> 9) & 3, mt = oi >> 11;
        int row = mt * 16 + (lane & 15);
        int k   = ks * 32 + ((lane >> 4) << 3) + e;
        unsigned short hi, lo;
        bsplit(R[row * (DDIM + 1) + k], hi, lo);
        dst[oi]           = hi;
        dst[MATELEM + oi] = lo;
    }
    // B-frag planes
    for (int oi = t; oi < MATELEM; oi += 256) {
        int e = oi & 7, lane = (oi >> 3) & 63, ks = (oi >> 9) & 3, nt = oi >> 11;
        int col = nt * 16 + (lane & 15);
        int k   = ks * 32 + ((lane >> 4) << 3) + e;
        unsigned short hi, lo;
        bsplit(R[k * (DDIM + 1) + col], hi, lo);
        dst[2 * MATELEM + oi] = hi;
        dst[3 * MATELEM + oi] = lo;
    }
}

// ---------------------------------------------------------------------------
// Kernel 2: in-place binary tree level. Block b: slot i0 = (2b)<<level gets
// src[i0] . src[i1], i1 = i0 + (1<<level). Split precision: 3 MFMAs per
// fragment pair. All operand loads are contiguous bf16x8 from frag planes.
// 8 waves; wave = mtile (16 output rows). Own-rows in-place write: race-free.
// ---------------------------------------------------------------------------
__global__ __launch_bounds__(512) void combine_kernel(
        unsigned short* __restrict__ buf, int level, int emit_a) {
    const int lane = threadIdx.x & 63;
    const int wave = threadIdx.x >> 6;       // = mtile
    const int lrow = lane & 15;
    const int lkhi = lane >> 4;
    const size_t i0 = (size_t)(2 * blockIdx.x) << level;
    const size_t i1 = i0 + ((size_t)1 << level);

    unsigned short*       DA = buf + i0 * MSTRIDE;               // A planes, in-place dst
    const unsigned short* BB = buf + i1 * MSTRIDE + 2 * MATELEM; // B planes of right mat

    f32x4 acc[8];
    #pragma unroll
    for (int n = 0; n < 8; ++n) acc[n] = (f32x4){0.0f, 0.0f, 0.0f, 0.0f};

    #pragma unroll
    for (int kstep = 0; kstep < 4; ++kstep) {
        const unsigned short* ap = DA + ((size_t)(wave * 4 + kstep) * 64 + lane) * 8;
        bf16x8 ahi = *reinterpret_cast<const bf16x8*>(ap);
        bf16x8 alo = *reinterpret_cast<const bf16x8*>(ap + MATELEM);
        #pragma unroll
        for (int n = 0; n < 8; ++n) {
            const unsigned short* bp = BB + ((size_t)(n * 4 + kstep) * 64 + lane) * 8;
            bf16x8 bhi = *reinterpret_cast<const bf16x8*>(bp);
            bf16x8 blo = *reinterpret_cast<const bf16x8*>(bp + MATELEM);
            acc[n] = __builtin_amdgcn_mfma_f32_16x16x32_bf16(ahi, bhi, acc[n], 0, 0, 0);
            acc[n] = __builtin_amdgcn_mfma_f32_16x16x32_bf16(alo, bhi, acc[n], 0, 0, 0);
            acc[n] = __builtin_amdgcn_mfma_f32_16x16x32_bf16(ahi, blo, acc[n], 0, 0, 0);
        }
    }

    // C/D: row = wave*16 + lkhi*4 + rr, col = n*16 + lrow
    unsigned short* DBp = DA + 2 * MATELEM;
    const int row0 = wave * 16 + lkhi * 4;
    #pragma unroll
    for (int n = 0; n < 8; ++n) {
        const int col = n * 16 + lrow;
        u16x4 chi, clo;
        #pragma unroll
        for (int rr = 0; rr < 4; ++rr) {
            unsigned short hi, lo;
            bsplit(acc[n][rr], hi, lo);
            chi[rr] = hi; clo[rr] = lo;
        }
        // B-plane: rr spans 4 consecutive e-slots -> one u16x4 per plane
        const size_t bflat = ((size_t)(n * 4 + (row0 >> 5)) * 64 +
                              ((row0 >> 3) & 3) * 16 + lrow) * 8 + (lkhi & 1) * 4;
        *reinterpret_cast<u16x4*>(DBp + bflat)           = chi;
        *reinterpret_cast<u16x4*>(DBp + MATELEM + bflat) = clo;
        // A-plane: scalar u16 stores (skipped at last level)
        if (emit_a) {
            #pragma unroll
            for (int rr = 0; rr < 4; ++rr) {
                const size_t aflat = ((size_t)(wave * 4 + (col >> 5)) * 64 +
                                      ((col >> 3) & 3) * 16 + lkhi * 4 + rr) * 8 + (col & 7);
                DA[aflat]           = chi[rr];
                DA[MATELEM + aflat] = clo[rr];
            }
        }
    }
}

// ---------------------------------------------------------------------------
// Kernel 3: out = x @ (Rhi + Rlo).  A-frags from contiguous fp32 loads of x
// (bf16 in-register), B-frags = contiguous bf16x8 from slot-0 B-planes
// (L2-resident).  Block = 4 waves x (32 rows x 128 cols) = 128 rows.
// ---------------------------------------------------------------------------
__global__ __launch_bounds__(256) void gemm_kernel(
        const float* __restrict__ x,
        const unsigned short* __restrict__ bfrag,   // B_hi; B_lo at +MATELEM
        float* __restrict__ out) {
    const int lane = threadIdx.x & 63;
    const int wave = threadIdx.x >> 6;
    const int lrow = lane & 15;
    const int lkhi = lane >> 4;
    const long brow = (long)blockIdx.x * 128 + wave * 32;

    f32x4 acc[2][8];
    #pragma unroll
    for (int m = 0; m < 2; ++m)
        #pragma unroll
        for (int n = 0; n < 8; ++n)
            acc[m][n] = (f32x4){0.0f, 0.0f, 0.0f, 0.0f};

    #pragma unroll
    for (int kstep = 0; kstep < 4; ++kstep) {
        const int k0 = kstep * 32 + lkhi * 8;
        bf16x8 afr[2];
        #pragma unroll
        for (int m = 0; m < 2; ++m) {
            const float* src = x + (brow + m * 16 + lrow) * (long)DDIM + k0;
            f32x4 lo = *reinterpret_cast<const f32x4*>(src);
            f32x4 hi = *reinterpret_cast<const f32x4*>(src + 4);
            union { bf16x8 v; unsigned short u[8]; } ua;
            #pragma unroll
            for (int e = 0; e < 4; ++e) {
                ua.u[e]     = f32_to_bf16_rne(lo[e]);
                ua.u[e + 4] = f32_to_bf16_rne(hi[e]);
            }
            afr[m] = ua.v;
        }
        #pragma unroll
        for (int n = 0; n < 8; ++n) {
            const unsigned short* bp = bfrag + ((size_t)(n * 4 + kstep) * 64 + lane) * 8;
            bf16x8 bhi = *reinterpret_cast<const bf16x8*>(bp);
            bf16x8 blo = *reinterpret_cast<const bf16x8*>(bp + MATELEM);
            acc[0][n] = __builtin_amdgcn_mfma_f32_16x16x32_bf16(afr[0], bhi, acc[0][n], 0, 0, 0);
            acc[0][n] = __builtin_amdgcn_mfma_f32_16x16x32_bf16(afr[0], blo, acc[0][n], 0, 0, 0);
            acc[1][n] = __builtin_amdgcn_mfma_f32_16x16x32_bf16(afr[1], bhi, acc[1][n], 0, 0, 0);
            acc[1][n] = __builtin_amdgcn_mfma_f32_16x16x32_bf16(afr[1], blo, acc[1][n], 0, 0, 0);
        }
    }

    // C/D: row = (lane>>4)*4 + r, col = lane&15 per 16x16 tile
    #pragma unroll
    for (int m = 0; m < 2; ++m) {
        #pragma unroll
        for (int r = 0; r < 4; ++r) {
            const long orow = brow + m * 16 + lkhi * 4 + r;
            #pragma unroll
            for (int n = 0; n < 8; ++n) {
                out[orow * DDIM + n * 16 + lrow] = acc[m][n][r];
            }
        }
    }
}

extern "C" void kernel_launch(void* const* d_in, const int* in_sizes, int n_in,
                              void* d_out, int out_size, void* d_ws, size_t ws_size,
                              hipStream_t stream) {
    (void)in_sizes; (void)n_in; (void)out_size; (void)ws_size;
    const float* x     = (const float*)d_in[0];
    const float* theta = (const float*)d_in[1];
    const int*   pairs = (const int*)d_in[2];
    float* out = (float*)d_out;

    // ws: 64 slots x 4 planes x 16384 bf16 = 8 MB. In-place tree: level l
    // block b consumes slots (2b)<<l and (2b+1)<<l, writes (2b)<<l.
    unsigned short* buf = (unsigned short*)d_ws;

    chunk_kernel<<<NCHUNK, 256, 0, stream>>>(theta, pairs, buf);
    for (int l = 0; l < 6; ++l)
        combine_kernel<<<(NCHUNK / 2) >> l, 512, 0, stream>>>(buf, l, (l < 5) ? 1 : 0);
    // final R lives in slot 0; gemm reads its B-frag hi/lo planes
    gemm_kernel<<<NROWS / 128, 256, 0, stream>>>(x, buf + 2 * MATELEM, out);
}

// Round 6
// 131.984 us; speedup vs baseline: 1.5826x; 1.1063x over previous
//
#include <hip/hip_runtime.h>
#include <hip/hip_bf16.h>

#define DDIM    128
#define NPAIRS  8128
#define NROWS   131072
#define NCHUNK  64
#define CPAIRS  127                 // pairs per chunk
#define MATELEM 16384               // elements per plane (128x128)
#define MSTRIDE (4 * MATELEM)       // planes per slot: A_hi, A_lo, B_hi, B_lo

typedef __attribute__((ext_vector_type(8))) short bf16x8;
typedef __attribute__((ext_vector_type(4))) float f32x4;
typedef __attribute__((ext_vector_type(4))) unsigned short u16x4;

// Fragment layouts for mfma_f32_16x16x32_bf16 (verified m89 mapping):
//  A-plane: value M[row][k] at ((row>>4)*4 + (k>>5))*512 + (((k>>3)&3)*16 + (row&15))*8 + (k&7)
//  B-plane: value M[k][col] at ((col>>4)*4 + (k>>5))*512 + (((k>>3)&3)*16 + (col&15))*8 + (k&7)
// -> per-lane loads are contiguous 16B; a wave's (tile,kstep) block is one 8KB region.

__device__ inline unsigned short f32_to_bf16_rne(float f) {
    unsigned u = __float_as_uint(f);
    u += 0x7fffu + ((u >> 16) & 1u);
    return (unsigned short)(u >> 16);
}
__device__ inline float bf16_to_f32(unsigned short h) {
    return __uint_as_float((unsigned)h << 16);
}
__device__ inline void bsplit(float v, unsigned short& hi, unsigned short& lo) {
    hi = f32_to_bf16_rne(v);
    lo = f32_to_bf16_rne(v - bf16_to_f32(hi));
}

// ---------------------------------------------------------------------------
// Kernel 1: block c builds M_c = prod of its 127 Givens rotations (fp32 in
// LDS). Emits A-planes (hi/lo) if c%4==0 (consumed as left operand) else
// B-planes (hi/lo).
// ---------------------------------------------------------------------------
__global__ __launch_bounds__(256) void chunk_kernel(
        const float* __restrict__ theta,
        const int*   __restrict__ pairs,
        unsigned short* __restrict__ buf) {
    __shared__ float  R[DDIM * (DDIM + 1)];
    __shared__ float2 cs[CPAIRS];
    __shared__ int2   ij[CPAIRS];

    const int t  = threadIdx.x;
    const int c  = blockIdx.x;
    const int p0 = c * CPAIRS;

    if (t < CPAIRS) {
        float th = theta[p0 + t];
        cs[t] = make_float2(cosf(th), sinf(th));
        ij[t] = make_int2(pairs[2 * (p0 + t)], pairs[2 * (p0 + t) + 1]);
    }
    if (t < DDIM) {
        float* row = &R[t * (DDIM + 1)];
        for (int q = 0; q < DDIM; ++q) row[q] = (q == t) ? 1.0f : 0.0f;
    }
    __syncthreads();

    if (t < DDIM) {
        float* row = &R[t * (DDIM + 1)];
        int   cur_i = ij[0].x;
        float ri    = row[cur_i];
        for (int p = 0; p < CPAIRS; ++p) {
            int2   v = ij[p];
            float2 a = cs[p];
            if (v.x != cur_i) {        // wave-uniform transition
                row[cur_i] = ri;
                cur_i = v.x;
                ri = row[cur_i];
            }
            float rj = row[v.y];
            row[v.y] = fmaf(a.y, ri, a.x * rj);      // s*xi + c*xj
            ri       = fmaf(a.x, ri, -(a.y * rj));   // c*xi - s*xj
        }
        row[cur_i] = ri;
    }
    __syncthreads();

    unsigned short* dst = buf + (size_t)c * MSTRIDE;
    if ((c & 3) == 0) {
        // A-frag planes
        for (int oi = t; oi < MATELEM; oi += 256) {
            int e = oi & 7, lane = (oi >> 3) & 63, ks = (oi >> 9) & 3, mt = oi >> 11;
            int row = mt * 16 + (lane & 15);
            int k   = ks * 32 + ((lane >> 4) << 3) + e;
            unsigned short hi, lo;
            bsplit(R[row * (DDIM + 1) + k], hi, lo);
            dst[oi]           = hi;
            dst[MATELEM + oi] = lo;
        }
    } else {
        // B-frag planes
        for (int oi = t; oi < MATELEM; oi += 256) {
            int e = oi & 7, lane = (oi >> 3) & 63, ks = (oi >> 9) & 3, nt = oi >> 11;
            int col = nt * 16 + (lane & 15);
            int k   = ks * 32 + ((lane >> 4) << 3) + e;
            unsigned short hi, lo;
            bsplit(R[k * (DDIM + 1) + col], hi, lo);
            dst[2 * MATELEM + oi] = hi;
            dst[3 * MATELEM + oi] = lo;
        }
    }
}

// ---------------------------------------------------------------------------
// Kernel 2: fan-in-4 combine. Block b (level l): slots base..base+3*stride,
// base = 4b*4^l, stride = 4^l. Chain P = s0.s1.s2.s3, intermediate T kept as
// f32 in LDS (row-major, stride 132). Wave w owns output rows [16w,16w+16):
// T reads/writes are wave-local -> zero barriers between chained matmuls.
// Split precision (3 MFMAs) against bf16 hi/lo operands. Emits A-planes if
// b%4==0 && level<2, else B-planes.
// ---------------------------------------------------------------------------
__global__ __launch_bounds__(512) void combine4_kernel(
        unsigned short* __restrict__ buf, int level) {
    __shared__ float T[DDIM * 132];   // 67584 B

    const int lane = threadIdx.x & 63;
    const int wave = threadIdx.x >> 6;       // = mtile
    const int lrow = lane & 15;
    const int lkhi = lane >> 4;
    const int b = blockIdx.x;
    const size_t stride = (size_t)1 << (2 * level);
    const size_t base   = (size_t)(4 * b) * stride;

    f32x4 acc[8];

    // ---- step 0: T = s[base] . s[base+stride]
    {
        const unsigned short* A  = buf + base * MSTRIDE;
        const unsigned short* BB = buf + (base + stride) * MSTRIDE + 2 * MATELEM;
        #pragma unroll
        for (int n = 0; n < 8; ++n) acc[n] = (f32x4){0.0f, 0.0f, 0.0f, 0.0f};
        #pragma unroll
        for (int kstep = 0; kstep < 4; ++kstep) {
            const unsigned short* ap = A + ((size_t)(wave * 4 + kstep) * 64 + lane) * 8;
            bf16x8 ahi = *reinterpret_cast<const bf16x8*>(ap);
            bf16x8 alo = *reinterpret_cast<const bf16x8*>(ap + MATELEM);
            #pragma unroll
            for (int n = 0; n < 8; ++n) {
                const unsigned short* bp = BB + ((size_t)(n * 4 + kstep) * 64 + lane) * 8;
                bf16x8 bhi = *reinterpret_cast<const bf16x8*>(bp);
                bf16x8 blo = *reinterpret_cast<const bf16x8*>(bp + MATELEM);
                acc[n] = __builtin_amdgcn_mfma_f32_16x16x32_bf16(ahi, bhi, acc[n], 0, 0, 0);
                acc[n] = __builtin_amdgcn_mfma_f32_16x16x32_bf16(alo, bhi, acc[n], 0, 0, 0);
                acc[n] = __builtin_amdgcn_mfma_f32_16x16x32_bf16(ahi, blo, acc[n], 0, 0, 0);
            }
        }
        #pragma unroll
        for (int n = 0; n < 8; ++n)
            #pragma unroll
            for (int rr = 0; rr < 4; ++rr)
                T[(wave * 16 + lkhi * 4 + rr) * 132 + n * 16 + lrow] = acc[n][rr];
    }

    // ---- steps: T = T . s[base+2*stride], then P = T . s[base+3*stride]
    for (int s = 2; s <= 3; ++s) {
        const unsigned short* BB = buf + (base + s * stride) * MSTRIDE + 2 * MATELEM;
        #pragma unroll
        for (int n = 0; n < 8; ++n) acc[n] = (f32x4){0.0f, 0.0f, 0.0f, 0.0f};
        #pragma unroll
        for (int kstep = 0; kstep < 4; ++kstep) {
            const float* ap = &T[(wave * 16 + lrow) * 132 + kstep * 32 + lkhi * 8];
            f32x4 a0 = *reinterpret_cast<const f32x4*>(ap);
            f32x4 a1 = *reinterpret_cast<const f32x4*>(ap + 4);
            union { bf16x8 v; unsigned short u[8]; } uh, ul;
            #pragma unroll
            for (int e = 0; e < 4; ++e) {
                unsigned short h0, l0, h1, l1;
                bsplit(a0[e], h0, l0);
                bsplit(a1[e], h1, l1);
                uh.u[e] = h0;     ul.u[e] = l0;
                uh.u[e + 4] = h1; ul.u[e + 4] = l1;
            }
            #pragma unroll
            for (int n = 0; n < 8; ++n) {
                const unsigned short* bp = BB + ((size_t)(n * 4 + kstep) * 64 + lane) * 8;
                bf16x8 bhi = *reinterpret_cast<const bf16x8*>(bp);
                bf16x8 blo = *reinterpret_cast<const bf16x8*>(bp + MATELEM);
                acc[n] = __builtin_amdgcn_mfma_f32_16x16x32_bf16(uh.v, bhi, acc[n], 0, 0, 0);
                acc[n] = __builtin_amdgcn_mfma_f32_16x16x32_bf16(ul.v, bhi, acc[n], 0, 0, 0);
                acc[n] = __builtin_amdgcn_mfma_f32_16x16x32_bf16(uh.v, blo, acc[n], 0, 0, 0);
            }
        }
        if (s < 3) {
            #pragma unroll
            for (int n = 0; n < 8; ++n)
                #pragma unroll
                for (int rr = 0; rr < 4; ++rr)
                    T[(wave * 16 + lkhi * 4 + rr) * 132 + n * 16 + lrow] = acc[n][rr];
        }
    }

    // ---- emit (hi/lo)
    const bool as_a = (level < 2) && ((b & 3) == 0);
    unsigned short* D = buf + base * MSTRIDE;
    if (as_a) {
        #pragma unroll
        for (int n = 0; n < 8; ++n) {
            const int col = n * 16 + lrow;
            #pragma unroll
            for (int rr = 0; rr < 4; ++rr) {
                unsigned short hi, lo;
                bsplit(acc[n][rr], hi, lo);
                const size_t aflat = ((size_t)(wave * 4 + (col >> 5)) * 64 +
                                      ((col >> 3) & 3) * 16 + lkhi * 4 + rr) * 8 + (col & 7);
                D[aflat]           = hi;
                D[MATELEM + aflat] = lo;
            }
        }
    } else {
        const int row0 = wave * 16 + lkhi * 4;
        #pragma unroll
        for (int n = 0; n < 8; ++n) {
            u16x4 chi, clo;
            #pragma unroll
            for (int rr = 0; rr < 4; ++rr) {
                unsigned short hi, lo;
                bsplit(acc[n][rr], hi, lo);
                chi[rr] = hi;
                clo[rr] = lo;
            }
            const size_t bflat = ((size_t)(n * 4 + (row0 >> 5)) * 64 +
                                  ((row0 >> 3) & 3) * 16 + lrow) * 8 + (lkhi & 1) * 4;
            *reinterpret_cast<u16x4*>(D + 2 * MATELEM + bflat) = chi;
            *reinterpret_cast<u16x4*>(D + 3 * MATELEM + bflat) = clo;
        }
    }
}

// ---------------------------------------------------------------------------
// Kernel 3: out = x @ Rhi.  B_hi staged once into LDS (frag-linear ->
// conflict-free ds_read_b128); C staged through LDS in two 64-row halves ->
// coalesced f32x4 global stores.  Block = 4 waves, 128 rows. 33.8 KB LDS ->
// 4 blocks/CU, entire 1024-block grid co-resident.
// ---------------------------------------------------------------------------
__global__ __launch_bounds__(256) void gemm_kernel(
        const float* __restrict__ x,
        const unsigned short* __restrict__ bfrag,   // B_hi plane of R
        float* __restrict__ out) {
    __shared__ float smem[64 * 132];                 // 33792 B; reused B -> C
    unsigned short* Blds = reinterpret_cast<unsigned short*>(smem);

    const int tid  = threadIdx.x;
    const int lane = tid & 63;
    const int wave = tid >> 6;
    const int lrow = lane & 15;
    const int lkhi = lane >> 4;
    const long brow = (long)blockIdx.x * 128 + wave * 32;

    // stage B_hi (32 KB) into LDS: 2048 x 16B chunks, coalesced
    #pragma unroll
    for (int i = 0; i < 8; ++i) {
        int idx = i * 256 + tid;
        reinterpret_cast<bf16x8*>(Blds)[idx] =
            reinterpret_cast<const bf16x8*>(bfrag)[idx];
    }
    __syncthreads();

    f32x4 acc[2][8];
    #pragma unroll
    for (int m = 0; m < 2; ++m)
        #pragma unroll
        for (int n = 0; n < 8; ++n)
            acc[m][n] = (f32x4){0.0f, 0.0f, 0.0f, 0.0f};

    #pragma unroll
    for (int kstep = 0; kstep < 4; ++kstep) {
        const int k0 = kstep * 32 + lkhi * 8;
        bf16x8 afr[2];
        #pragma unroll
        for (int m = 0; m < 2; ++m) {
            const float* src = x + (brow + m * 16 + lrow) * (long)DDIM + k0;
            f32x4 lo = *reinterpret_cast<const f32x4*>(src);
            f32x4 hi = *reinterpret_cast<const f32x4*>(src + 4);
            union { bf16x8 v; unsigned short u[8]; } ua;
            #pragma unroll
            for (int e = 0; e < 4; ++e) {
                ua.u[e]     = f32_to_bf16_rne(lo[e]);
                ua.u[e + 4] = f32_to_bf16_rne(hi[e]);
            }
            afr[m] = ua.v;
        }
        #pragma unroll
        for (int n = 0; n < 8; ++n) {
            bf16x8 bhi = *reinterpret_cast<const bf16x8*>(
                Blds + ((n * 4 + kstep) * 64 + lane) * 8);
            acc[0][n] = __builtin_amdgcn_mfma_f32_16x16x32_bf16(afr[0], bhi, acc[0][n], 0, 0, 0);
            acc[1][n] = __builtin_amdgcn_mfma_f32_16x16x32_bf16(afr[1], bhi, acc[1][n], 0, 0, 0);
        }
    }

    // C/D layout: row = (lane>>4)*4 + r per 16-tile, col = n*16 + lrow.
    // Two 64-row halves through LDS (stride 132: 2-way write, even read).
    #pragma unroll
    for (int h = 0; h < 2; ++h) {
        __syncthreads();               // h=0: B reads done; h=1: prev reads done
        if ((wave >> 1) == h) {
            const int r0 = (wave & 1) * 32;
            #pragma unroll
            for (int m = 0; m < 2; ++m)
                #pragma unroll
                for (int rr = 0; rr < 4; ++rr) {
                    const int lr = r0 + m * 16 + lkhi * 4 + rr;
                    #pragma unroll
                    for (int n = 0; n < 8; ++n)
                        smem[lr * 132 + n * 16 + lrow] = acc[m][n][rr];
                }
        }
        __syncthreads();
        const long gr0 = (long)blockIdx.x * 128 + h * 64;
        #pragma unroll
        for (int i = 0; i < 8; ++i) {
            int idx = i * 256 + tid;           // 2048 chunks = 64 rows x 32
            int lr  = idx >> 5;
            int c4  = (idx & 31) * 4;
            *reinterpret_cast<f32x4*>(&out[(gr0 + lr) * DDIM + c4]) =
                *reinterpret_cast<const f32x4*>(&smem[lr * 132 + c4]);
        }
    }
}

extern "C" void kernel_launch(void* const* d_in, const int* in_sizes, int n_in,
                              void* d_out, int out_size, void* d_ws, size_t ws_size,
                              hipStream_t stream) {
    (void)in_sizes; (void)n_in; (void)out_size; (void)ws_size;
    const float* x     = (const float*)d_in[0];
    const float* theta = (const float*)d_in[1];
    const int*   pairs = (const int*)d_in[2];
    float* out = (float*)d_out;

    // ws: 64 slots x 4 planes x 16384 bf16 = 8 MB.
    unsigned short* buf = (unsigned short*)d_ws;

    chunk_kernel<<<NCHUNK, 256, 0, stream>>>(theta, pairs, buf);
    combine4_kernel<<<16, 512, 0, stream>>>(buf, 0);   // 64 -> 16
    combine4_kernel<<< 4, 512, 0, stream>>>(buf, 1);   // 16 -> 4
    combine4_kernel<<< 1, 512, 0, stream>>>(buf, 2);   // 4  -> 1 (B-planes @ slot 0)
    gemm_kernel<<<NROWS / 128, 256, 0, stream>>>(x, buf + 2 * MATELEM, out);
}